// Round 6
// baseline (104.448 us; speedup 1.0000x reference)
//
#include <hip/hip_runtime.h>
#include <math.h>

#define W 2048
#define NB 16
#define TLEN 88200
#define NF 337
#define NFP 169      // ceil(337/2) frame-pairs per batch
#define NMIDI 80

typedef __attribute__((ext_vector_type(8))) short short8;
typedef __attribute__((ext_vector_type(4))) float f32x4;

__device__ __forceinline__ int swix(int t) { return t ^ (((t >> 5) & 7) << 2); }
// Non-linear quad rotation: distinct bank-quads for stride-1 AND stride-2 octet walks.
__device__ __forceinline__ int quadrot(int oct, int s) {
    return (s + 5 * (oct >> 1) + 4 * (oct & 1)) & 7;
}
// window of 8 bf16 starting at frame-pair element S (S in [-256, 2304))
__device__ __forceinline__ int xoff(int S) {
    int s = S & 7;
    int oct = (S + 256) >> 3;
    return (oct << 6) + (quadrot(oct, s) << 3);
}
__device__ __forceinline__ unsigned int f2bf(float x) {  // RNE f32->bf16
    unsigned u = __float_as_uint(x);
    u += 0x7FFF + ((u >> 16) & 1);
    return u >> 16;
}

#define MM(acc, A_, B_) acc = __builtin_amdgcn_mfma_f32_16x16x32_bf16(A_, B_, acc, 0, 0, 0)
#define MM4(acc, A_) { MM(acc, A_[0], bF[0]); MM(acc, A_[1], bF[1]); MM(acc, A_[2], bF[2]); MM(acc, A_[3], bF[3]); }
#define MM4S(acc, A_, B3) { MM(acc, A_[0], bF[0]); MM(acc, A_[1], bF[1]); MM(acc, A_[2], bF[2]); MM(acc, A_[3], B3); }
#define LDA(dst, gk) { dst[0] = *(const short8*)(lds_x + oA[0] + (gk)*1024); \
                       dst[1] = *(const short8*)(lds_x + oA[1] + (gk)*1024); \
                       dst[2] = *(const short8*)(lds_x + oA[2] + (gk)*1024); \
                       dst[3] = *(const short8*)(lds_x + oA[3] + (gk)*1024); }
#define LDB(gk)      { bF[0] = *(const short8*)(lds_x + oB[0] + (gk)*1024); \
                       bF[1] = *(const short8*)(lds_x + oB[1] + (gk)*1024); \
                       bF[2] = *(const short8*)(lds_x + oB[2] + (gk)*1024); \
                       bF[3] = *(const short8*)(lds_x + oB[3] + (gk)*1024); }

__global__ __launch_bounds__(256) void yin_kernel(const float* __restrict__ x,
                                                  float* __restrict__ out) {
    const int p = blockIdx.x, b = blockIdx.y;
    const int tid = threadIdx.x;
    const int lane = tid & 63, wv = tid >> 6;
    const bool lastp = (p == NFP - 1);

    __shared__ unsigned short lds_x[20480];  // shared pair stream: 320 oct-groups x 64
    __shared__ unsigned short padA[512];     // f1 low-A pad (zero-headed), linear stride-8 windows
    __shared__ unsigned short padB0[320];    // f0 B-boundary (zero >= pair 2048)
    __shared__ unsigned short padB1[320];    // f1 B-boundary (zero >= pair 2304)
    __shared__ float cumE[2305];             // extended energy cumsum [0, 2304], swizzled
    __shared__ float dfc[4096];              // df/cmndf, frames 0,1
    __shared__ float wsum[4];
    __shared__ float wdsum[8];

    const float* xp = x + (size_t)b * TLEN + (size_t)p * 512;
    const float4* xq = (const float4*)xp;          // 16B aligned
    const int elim4 = lastp ? 546 : 0x7FFFFFFF;    // float4-idx limit (zero beyond, last pair)

    // ---------------- Phase A: staging ----------------
    float v[16];
    {
        float4 q[4];
        #pragma unroll
        for (int qi = 0; qi < 4; ++qi) {
            int idx = 2 * tid + qi;
            q[qi] = (idx < elim4) ? xq[idx] : make_float4(0.f, 0.f, 0.f, 0.f);
        }
        v[0]=q[0].x; v[1]=q[0].y; v[2]=q[0].z; v[3]=q[0].w;
        v[4]=q[1].x; v[5]=q[1].y; v[6]=q[1].z; v[7]=q[1].w;
        v[8]=q[2].x; v[9]=q[2].y; v[10]=q[2].z; v[11]=q[2].w;
        v[12]=q[3].x; v[13]=q[3].y; v[14]=q[3].z; v[15]=q[3].w;
    }
    float pj[8];
    float etot = 0.f;
    #pragma unroll
    for (int j = 0; j < 8; ++j) { etot = fmaf(v[j], v[j], etot); pj[j] = etot; }
    {
        unsigned D[14];
        #pragma unroll
        for (int i = 0; i < 14; ++i) D[i] = f2bf(v[i]) | (f2bf(v[i + 1]) << 16);
        const int oct = tid + 32;
        #pragma unroll
        for (int s = 0; s < 8; ++s)
            *(uint4*)(lds_x + (oct << 6) + (quadrot(oct, s) << 3)) =
                make_uint4(D[s], D[s + 2], D[s + 4], D[s + 6]);
    }
    {   // zero pad octets [0,32): pair-stream elements [-256, 0)
        int po = tid >> 3, s = tid & 7;
        *(uint4*)(lds_x + (po << 6) + (quadrot(po, s) << 3)) = make_uint4(0, 0, 0, 0);
    }
    // secondary staging (tid<32): elements [2048+8tid, 2048+8tid+16), oct 288+tid
    float p2j[8];
    if (tid < 32) {
        float v2[16];
        float4 q[4];
        #pragma unroll
        for (int qi = 0; qi < 4; ++qi) {
            int idx = 512 + 2 * tid + qi;
            q[qi] = (idx < elim4) ? xq[idx] : make_float4(0.f, 0.f, 0.f, 0.f);
        }
        v2[0]=q[0].x; v2[1]=q[0].y; v2[2]=q[0].z; v2[3]=q[0].w;
        v2[4]=q[1].x; v2[5]=q[1].y; v2[6]=q[1].z; v2[7]=q[1].w;
        v2[8]=q[2].x; v2[9]=q[2].y; v2[10]=q[2].z; v2[11]=q[2].w;
        v2[12]=q[3].x; v2[13]=q[3].y; v2[14]=q[3].z; v2[15]=q[3].w;
        float e2 = 0.f;
        #pragma unroll
        for (int j = 0; j < 8; ++j) { e2 = fmaf(v2[j], v2[j], e2); p2j[j] = e2; }
        unsigned D2[14];
        #pragma unroll
        for (int i = 0; i < 14; ++i) D2[i] = f2bf(v2[i]) | (f2bf(v2[i + 1]) << 16);
        const int oct = 288 + tid;
        #pragma unroll
        for (int s = 0; s < 8; ++s)
            *(uint4*)(lds_x + (oct << 6) + (quadrot(oct, s) << 3)) =
                make_uint4(D2[s], D2[s + 2], D2[s + 4], D2[s + 6]);
    }
    // padB0: windows S in [2016, 2056), zero at >= 2048 (f0's frame end)
    if (tid >= 64 && tid < 104) {
        int S = 2016 + (tid - 64);
        int oc = S >> 3, s = S & 7;
        unsigned u[8];
        #pragma unroll
        for (int j = 0; j < 8; ++j) {
            int e = S + j;
            float val = (e < 2048) ? xp[e] : 0.0f;
            u[j] = f2bf(val);
        }
        *(uint4*)(padB0 + ((oc - 252) << 6) + (quadrot(oc, s) << 3)) =
            make_uint4(u[0]|(u[1]<<16), u[2]|(u[3]<<16), u[4]|(u[5]<<16), u[6]|(u[7]<<16));
    }
    // padB1: windows S in [2272, 2312), zero at >= 2304 (f1's frame end)
    if (tid >= 104 && tid < 144) {
        int S = 2272 + (tid - 104);
        int oc = S >> 3, s = S & 7;
        unsigned u[8];
        #pragma unroll
        for (int j = 0; j < 8; ++j) {
            int e = S + j;
            float val = 0.0f;
            if (!lastp && e < 2304) val = xp[e];
            u[j] = f2bf(val);
        }
        *(uint4*)(padB1 + ((oc - 284) << 6) + (quadrot(oc, s) << 3)) =
            make_uint4(u[0]|(u[1]<<16), u[2]|(u[3]<<16), u[4]|(u[5]<<16), u[6]|(u[7]<<16));
    }
    // padA: f1 low-A windows, pair-coord starts S = 16+8w, zero below pair-coord 256
    if (tid >= 144 && tid < 206) {
        int w = tid - 144;
        int t0 = -240 + 8 * w;                 // f1-frame coords
        unsigned u[8];
        #pragma unroll
        for (int j = 0; j < 8; ++j) {
            int t = t0 + j;
            float val = (t >= 0) ? xp[256 + t] : 0.0f;
            u[j] = f2bf(val);
        }
        *(uint4*)(padA + 8 * w) =
            make_uint4(u[0]|(u[1]<<16), u[2]|(u[3]<<16), u[4]|(u[5]<<16), u[6]|(u[7]<<16));
    }

    // wave inclusive scan of per-thread energy totals
    float inc = etot;
    #pragma unroll
    for (int d = 1; d < 64; d <<= 1) {
        float t = __shfl_up(inc, d, 64);
        if (lane >= d) inc += t;
    }
    if (lane == 63) wsum[wv] = inc;

    __syncthreads();  // B1: lds_x + pads + wsum ready

    // energy cumsum (exclusive): cumE[t] = sum_{i<t} x^2, t in [0, 2304]
    {
        float base = inc - etot;
        if (wv > 0) base += wsum[0];
        if (wv > 1) base += wsum[1];
        if (wv > 2) base += wsum[2];
        f32x4 q0 = {base, base + pj[0], base + pj[1], base + pj[2]};
        f32x4 q1 = {base + pj[3], base + pj[4], base + pj[5], base + pj[6]};
        *(f32x4*)(cumE + swix(8 * tid)) = q0;
        *(f32x4*)(cumE + swix(8 * tid + 4)) = q1;
        // NOTE: cumE[2048] is written by the extended block below (tid 0), not here —
        // avoids a WAW race with a different summation order.
    }
    if (tid < 32) {  // extended part [2048, 2304]
        float E2048 = wsum[0] + wsum[1] + wsum[2] + wsum[3];
        float e2tot = p2j[7];
        float inc2 = e2tot;
        #pragma unroll
        for (int d = 1; d < 32; d <<= 1) {
            float t = __shfl_up(inc2, d, 64);
            if (lane >= d) inc2 += t;
        }
        float baseE = E2048 + inc2 - e2tot;
        f32x4 q0 = {baseE, baseE + p2j[0], baseE + p2j[1], baseE + p2j[2]};
        f32x4 q1 = {baseE + p2j[3], baseE + p2j[4], baseE + p2j[5], baseE + p2j[6]};
        *(f32x4*)(cumE + swix(2048 + 8 * tid)) = q0;
        *(f32x4*)(cumE + swix(2048 + 8 * tid + 4)) = q1;
        if (tid == 31) cumE[2304] = baseE + p2j[7];
    }

    // ---------------- Phase C: MFMA, 2 frames x paired tau-blocks ----------------
    const int L = lane & 15;
    const int q8 = (lane >> 4) << 3;           // k-quarter offset, {0,8,16,24}
    const int bA = 2 * wv;
    const int KA4 = 16 - 4 * wv;               // f0 group count (group = 128 elements)
    const int P = KA4 >> 2;
    const bool w3 = (wv == 3);

    int oA[4], oB[4];
    #pragma unroll
    for (int i = 0; i < 4; ++i) {
        oA[i] = xoff(32 * i + q8 - 16 * L);
        oB[i] = xoff(32 * i + q8 + L + 256 * bA);
    }
    const int SB0 = 2016 + q8 + L;
    const int oPB0 = (((SB0 >> 3) - 252) << 6) + (quadrot(SB0 >> 3, SB0 & 7) << 3);
    const int SB1 = 2272 + q8 + L;
    const int oPB1 = (((SB1 >> 3) - 284) << 6) + (quadrot(SB1 >> 3, SB1 & 7) << 3);

    short8 sA0[4], sA1[4], sA2[4], sA3[4], aP2[4], aP3[4], bF[4];
    #pragma unroll
    for (int i = 0; i < 4; ++i) {
        aP2[i] = *(const short8*)(padA + (256 + 32 * i + q8 - 16 * L) - 16);
        aP3[i] = *(const short8*)(padA + (384 + 32 * i + q8 - 16 * L) - 16);
    }
    short8 bp0 = *(const short8*)(padB0 + oPB0);

    f32x4 acc0A = {0.f,0.f,0.f,0.f}, acc0B = {0.f,0.f,0.f,0.f};
    f32x4 acc1A = {0.f,0.f,0.f,0.f}, acc1B = {0.f,0.f,0.f,0.f};

    // prologue g=0,1 (f0.accA only)
    LDA(sA0, 0); LDB(0); MM4(acc0A, sA0);
    LDA(sA1, 1); LDB(1); MM4(acc0A, sA1);
    // peeled block g=2..5
    LDA(sA2, 2); LDB(2);
    MM4(acc0A, sA2); MM4(acc0B, sA0); MM4(acc1A, aP2);
    LDA(sA3, 3); LDB(3);
    {
        short8 b3 = w3 ? bp0 : bF[3];          // f0 boundary for wv3 (KA4-1 == 3)
        MM4S(acc0A, sA3, b3); MM4S(acc0B, sA1, b3); MM4(acc1A, aP3);
    }
    LDA(sA0, 4); LDB(4);
    if (!w3) { MM4(acc0A, sA0); MM4(acc0B, sA2); }
    MM4(acc1A, sA0); MM4(acc1B, aP2);
    LDA(sA1, 5);
    {
        bF[0] = *(const short8*)(lds_x + oB[0] + 5 * 1024);
        bF[1] = *(const short8*)(lds_x + oB[1] + 5 * 1024);
        bF[2] = *(const short8*)(lds_x + oB[2] + 5 * 1024);
        const unsigned short* pb3 = w3 ? (padB1 + oPB1) : (lds_x + oB[3] + 5 * 1024);
        bF[3] = *(const short8*)pb3;           // f1 boundary for wv3 (KA4+1 == 5)
    }
    if (!w3) { MM4(acc0A, sA1); MM4(acc0B, sA3); }
    MM4(acc1A, sA1); MM4(acc1B, aP3);

    // main blocks
    for (int pp = 1; pp < P; ++pp) {
        const int g0 = 2 + 4 * pp;
        const bool lastP = (pp == P - 1);
        LDA(sA2, g0); LDB(g0);
        MM4(acc0A, sA2); MM4(acc0B, sA0); MM4(acc1A, sA2); MM4(acc1B, sA0);
        LDA(sA3, g0 + 1); LDB(g0 + 1);
        {
            short8 b3 = lastP ? bp0 : bF[3];   // g0+1 == KA4-1 at lastP
            MM4S(acc0A, sA3, b3); MM4S(acc0B, sA1, b3);
            MM4(acc1A, sA3); MM4(acc1B, sA1);
        }
        LDA(sA0, g0 + 2); LDB(g0 + 2);
        if (!lastP) { MM4(acc0A, sA0); MM4(acc0B, sA2); }
        MM4(acc1A, sA0); MM4(acc1B, sA2);
        LDA(sA1, g0 + 3);
        {
            bF[0] = *(const short8*)(lds_x + oB[0] + (g0 + 3) * 1024);
            bF[1] = *(const short8*)(lds_x + oB[1] + (g0 + 3) * 1024);
            bF[2] = *(const short8*)(lds_x + oB[2] + (g0 + 3) * 1024);
            const unsigned short* pb3 = lastP ? (padB1 + oPB1)
                                              : (lds_x + oB[3] + (g0 + 3) * 1024);
            bF[3] = *(const short8*)pb3;       // g0+3 == KA4+1 at lastP
        }
        if (!lastP) { MM4(acc0A, sA1); MM4(acc0B, sA3); }
        MM4(acc1A, sA1); MM4(acc1B, sA3);
    }

    __syncthreads();  // B2: cumE complete, accs done

    // ---------------- Phase D: df ----------------
    {
        const int hi64 = (lane >> 4) << 6;
        {   // frame 0
            const float cW = cumE[2048], c0 = cumE[0];
            #pragma unroll
            for (int r = 0; r < 4; ++r) {
                int tau = (bA << 8) + hi64 + (r << 4) + L;
                dfc[swix(tau)] = cumE[swix(2048 - tau)] + cW - cumE[swix(tau)] - c0 - 2.0f * acc0A[r];
            }
            #pragma unroll
            for (int r = 0; r < 4; ++r) {
                int tau = ((bA + 1) << 8) + hi64 + (r << 4) + L;
                dfc[swix(tau)] = cumE[swix(2048 - tau)] + cW - cumE[swix(tau)] - c0 - 2.0f * acc0B[r];
            }
        }
        {   // frame 1 (offset 256)
            const float cW = cumE[2304], c0 = cumE[swix(256)];
            #pragma unroll
            for (int r = 0; r < 4; ++r) {
                int tau = (bA << 8) + hi64 + (r << 4) + L;
                dfc[2048 + swix(tau)] = cumE[swix(2304 - tau)] + cW - cumE[swix(tau + 256)] - c0 - 2.0f * acc1A[r];
            }
            #pragma unroll
            for (int r = 0; r < 4; ++r) {
                int tau = ((bA + 1) << 8) + hi64 + (r << 4) + L;
                dfc[2048 + swix(tau)] = cumE[swix(2304 - tau)] + cW - cumE[swix(tau + 256)] - c0 - 2.0f * acc1B[r];
            }
        }
    }

    __syncthreads();  // B3: df ready

    // ---------------- Phase E: cmndf, both frames ----------------
    float dv0[8], dv1[8], ex0, ex1;
    {
        int t0 = (wv << 9) + (lane << 3);
        f32x4 qa = *(const f32x4*)(dfc + swix(t0));
        f32x4 qb = *(const f32x4*)(dfc + swix(t0 + 4));
        f32x4 qc = *(const f32x4*)(dfc + 2048 + swix(t0));
        f32x4 qd = *(const f32x4*)(dfc + 2048 + swix(t0 + 4));
        dv0[0]=qa.x; dv0[1]=qa.y; dv0[2]=qa.z; dv0[3]=qa.w;
        dv0[4]=qb.x; dv0[5]=qb.y; dv0[6]=qb.z; dv0[7]=qb.w;
        dv1[0]=qc.x; dv1[1]=qc.y; dv1[2]=qc.z; dv1[3]=qc.w;
        dv1[4]=qd.x; dv1[5]=qd.y; dv1[6]=qd.z; dv1[7]=qd.w;
        if (t0 == 0) { dv0[0] = 0.f; dv1[0] = 0.f; }
        float s0 = dv0[0]+dv0[1]+dv0[2]+dv0[3]+dv0[4]+dv0[5]+dv0[6]+dv0[7];
        float s1 = dv1[0]+dv1[1]+dv1[2]+dv1[3]+dv1[4]+dv1[5]+dv1[6]+dv1[7];
        float i0 = s0, i1 = s1;
        #pragma unroll
        for (int d = 1; d < 64; d <<= 1) {
            float t0s = __shfl_up(i0, d, 64);
            float t1s = __shfl_up(i1, d, 64);
            if (lane >= d) { i0 += t0s; i1 += t1s; }
        }
        ex0 = i0 - s0; ex1 = i1 - s1;
        if (lane == 63) { wdsum[wv] = i0; wdsum[4 + wv] = i1; }
    }
    __syncthreads();  // B4: wave sums ready
    {
        int t0 = (wv << 9) + (lane << 3);
        float run0 = ex0, run1 = ex1;
        if (wv > 0) { run0 += wdsum[0]; run1 += wdsum[4]; }
        if (wv > 1) { run0 += wdsum[1]; run1 += wdsum[5]; }
        if (wv > 2) { run0 += wdsum[2]; run1 += wdsum[6]; }
        f32x4 o0a, o0b, o1a, o1b;
        #pragma unroll
        for (int j = 0; j < 8; ++j) {
            run0 += dv0[j];
            run1 += dv1[j];
            float y0 = (float)(t0 + j) * dv0[j] / (run0 + 1e-8f);
            float y1 = (float)(t0 + j) * dv1[j] / (run1 + 1e-8f);
            if (t0 + j == 0) { y0 = 1.0f; y1 = 1.0f; }
            if (j < 4) { o0a[j] = y0; o1a[j] = y1; } else { o0b[j-4] = y0; o1b[j-4] = y1; }
        }
        *(f32x4*)(dfc + swix(t0)) = o0a;
        *(f32x4*)(dfc + swix(t0 + 4)) = o0b;
        *(f32x4*)(dfc + 2048 + swix(t0)) = o1a;
        *(f32x4*)(dfc + 2048 + swix(t0 + 4)) = o1b;
    }
    __syncthreads();  // B5: cmndf ready

    // ---------------- Phase F: sample 80 midi lags x 2 frames ----------------
    if (tid < 2 * NMIDI) {
        int j = (tid >= NMIDI) ? 1 : 0;
        int m = tid - NMIDI * j;
        int fr = 2 * p + j;
        if (fr < NF) {
            float c = 22050.0f / (440.0f * exp2f((float)(m - 64) * (1.0f / 12.0f)));
            int fl = (int)c;
            float frac = c - (float)fl;
            float cf = dfc[(j << 11) + swix(fl)];
            float cc = dfc[(j << 11) + swix(fl + 1)];
            out[(size_t)b * (NMIDI * NF) + (size_t)m * NF + fr] = fmaf(cc - cf, frac, cf);
        }
    }
}

extern "C" void kernel_launch(void* const* d_in, const int* in_sizes, int n_in,
                              void* d_out, int out_size, void* d_ws, size_t ws_size,
                              hipStream_t stream) {
    const float* x = (const float*)d_in[0];
    float* out = (float*)d_out;
    dim3 grid(NFP, NB);
    yin_kernel<<<grid, 256, 0, stream>>>(x, out);
}